// Round 8
// baseline (376.579 us; speedup 1.0000x reference)
//
#include <hip/hip_runtime.h>

typedef unsigned short u16;
typedef __attribute__((ext_vector_type(8))) __bf16 bf16x8;
typedef __attribute__((ext_vector_type(4))) float floatx4;

#define DEV static __device__ __forceinline__

DEV float lo2f(unsigned v){ return __uint_as_float(v << 16); }
DEV float hi2f(unsigned v){ return __uint_as_float(v & 0xffff0000u); }
DEV u16 f2b(float f){
  unsigned u = __float_as_uint(f);
  return (u16)((u + 0x7fffu + ((u >> 16) & 1u)) >> 16);
}
// fast erf-gelu: Abramowitz-Stegun 7.1.26, |err_erf| < 1.5e-7
DEV float geluf(float x){
  float u  = x * 0.70710678118654752440f;
  float au = fabsf(u);
  float t  = __builtin_amdgcn_rcpf(fmaf(0.3275911f, au, 1.0f));
  float p  = t*(0.254829592f + t*(-0.284496736f + t*(1.421413741f +
             t*(-1.453152027f + t*1.061405429f))));
  float e  = __expf(-au*au);
  float E  = fmaf(-p, e, 1.0f);
  float er = copysignf(E, u);
  return 0.5f * x * (1.0f + er);
}

// ---------------------------------------------------------------------------
// Weight pre-pack (R6-proven): all weights as contiguous 32 KB N=128 panels
//   dst[off + ((kk*128 + n)*4 + q)*8 + j] = src[(kk*32+q*8+j)*srcN + nbase + n]
// lw1 / headw (N=256 sources) split into two column panels.
// ---------------------------------------------------------------------------
__global__ __launch_bounds__(256) void k_pack(
    const float* __restrict__ lw1, const float* __restrict__ lw2, const float* __restrict__ poolw,
    const float* __restrict__ mw1, const float* __restrict__ mw2, const float* __restrict__ uw1,
    const float* __restrict__ uw2, const float* __restrict__ bcw, const float* __restrict__ headw,
    u16* __restrict__ dst)
{
  int b = blockIdx.x;
  const float* src; int srcN, nbase = 0, off;
  if      (b < 64) {            src = lw1;  srcN = 256; nbase = 0;   off = 0;      }
  else if (b < 128){ b -= 64;   src = lw1;  srcN = 256; nbase = 128; off = 16384;  }
  else if (b < 256){ b -= 128;  src = lw2;  srcN = 128;              off = 32768;  }
  else if (b < 320){ b -= 256;  src = poolw;srcN = 128;              off = 65536;  }
  else if (b < 384){ b -= 320;  src = mw1;  srcN = 128;              off = 81920;  }
  else if (b < 448){ b -= 384;  src = mw1 + 16384; srcN = 128;       off = 98304;  }
  else if (b < 512){ b -= 448;  src = mw2;  srcN = 128;              off = 114688; }
  else if (b < 640){ b -= 512;  src = uw1;  srcN = 128;              off = 131072; }
  else if (b < 704){ b -= 640;  src = uw2;  srcN = 128;              off = 163840; }
  else if (b < 768){ b -= 704;  src = bcw;  srcN = 128;              off = 180224; }
  else if (b < 832){ b -= 768;  src = headw;srcN = 256; nbase = 0;   off = 196608; }
  else             { b -= 832;  src = headw;srcN = 256; nbase = 128; off = 212992; }
  int e = b * 256 + threadIdx.x;
  int j = e & 7, q = (e >> 3) & 3, rest = e >> 5;
  int n = rest & 127, kk = rest >> 7;
  int k = kk * 32 + q * 8 + j;
  dst[off + e] = f2b(src[k * srcN + nbase + n]);
}

// ---------------------------------------------------------------------------
// Shared MFMA helper: 16-row tile x 128 cols, K=128, B = N=128 panel (LDS or
// global; fragment layout identical).
// ---------------------------------------------------------------------------
DEV void mma8(floatx4* acc, const u16* Arow, int ap, const u16* W, int l15, int q){
  const u16* ar = Arow + l15 * ap + q * 8;
#pragma unroll
  for (int kk = 0; kk < 4; kk++){
    bf16x8 av = *(const bf16x8*)(ar + kk * 32);
#pragma unroll
    for (int nt = 0; nt < 8; nt++){
      bf16x8 bv = *(const bf16x8*)(W + (size_t)((kk * 128 + nt * 16 + l15) * 4 + q) * 8);
      acc[nt] = __builtin_amdgcn_mfma_f32_16x16x32_bf16(av, bv, acc[nt], 0, 0, 0);
    }
  }
}

// ---------------------------------------------------------------------------
// k_table (R7-proven, unchanged): table[tok*8+c] = local row for (tok,c).
// 32 blocks x 256 threads, 64 rows/block, 4-phase GEMM, weights from L2.
// ---------------------------------------------------------------------------
__global__ __launch_bounds__(256) void k_table(
    const float* __restrict__ emb, const float* __restrict__ pos,
    const u16* __restrict__ lw1p, const float* __restrict__ lb1,
    const u16* __restrict__ lw2p, const float* __restrict__ lb2,
    const float* __restrict__ g, const float* __restrict__ bb,
    u16* __restrict__ table)
{
  __shared__ __align__(16) u16 sA[64][136];
  __shared__ __align__(16) u16 sY[64][136];
  const int tid = threadIdx.x;
  const int m0 = blockIdx.x * 64;
  const int r = tid >> 2, sg = tid & 3;
  {
    const int row = m0 + r, tok = row >> 3, c = row & 7;
    const float4* e4 = (const float4*)(emb + (size_t)tok * 128 + sg * 32);
    const float4* p4 = (const float4*)(pos + c * 128 + sg * 32);
    float h[32];
    float s = 0.f, s2 = 0.f;
#pragma unroll
    for (int i = 0; i < 8; i++){
      float4 ev = e4[i], pv = p4[i];
      float v0 = ev.x + pv.x, v1 = ev.y + pv.y, v2 = ev.z + pv.z, v3 = ev.w + pv.w;
      h[i * 4 + 0] = v0; h[i * 4 + 1] = v1; h[i * 4 + 2] = v2; h[i * 4 + 3] = v3;
      s += v0 + v1 + v2 + v3;
      s2 += v0 * v0 + v1 * v1 + v2 * v2 + v3 * v3;
    }
    s  += __shfl_xor(s, 1, 64);   s  += __shfl_xor(s, 2, 64);
    s2 += __shfl_xor(s2, 1, 64);  s2 += __shfl_xor(s2, 2, 64);
    float mu = s * (1.f / 128.f);
    float rs = rsqrtf(s2 * (1.f / 128.f) - mu * mu + 1e-5f);
#pragma unroll
    for (int i = 0; i < 32; i++){
      int col = sg * 32 + i;
      sA[r][col] = f2b((h[i] - mu) * rs * g[col] + bb[col]);
    }
  }
  __syncthreads();
  const int lane = tid & 63, wv = tid >> 6, l15 = lane & 15, q = lane >> 4;
  floatx4 a2[8];
#pragma unroll
  for (int i = 0; i < 8; i++) a2[i] = (floatx4)(0.0f);
  {
    floatx4 a1[8];
#pragma unroll
    for (int i = 0; i < 8; i++) a1[i] = (floatx4)(0.0f);
    mma8(a1, &sA[wv * 16][0], 136, lw1p, l15, q);
#pragma unroll
    for (int nt = 0; nt < 8; nt++){
      int col = nt * 16 + l15;
      float bval = lb1[col];
#pragma unroll
      for (int rr = 0; rr < 4; rr++)
        sY[wv * 16 + q * 4 + rr][col] = f2b(geluf(a1[nt][rr] + bval));
    }
  }
  __syncthreads();
  mma8(a2, &sY[wv * 16][0], 136, lw2p, l15, q);
  __syncthreads();
  {
    floatx4 a1[8];
#pragma unroll
    for (int i = 0; i < 8; i++) a1[i] = (floatx4)(0.0f);
    mma8(a1, &sA[wv * 16][0], 136, lw1p + 16384, l15, q);
#pragma unroll
    for (int nt = 0; nt < 8; nt++){
      int col = nt * 16 + l15;
      float bval = lb1[128 + col];
#pragma unroll
      for (int rr = 0; rr < 4; rr++)
        sY[wv * 16 + q * 4 + rr][col] = f2b(geluf(a1[nt][rr] + bval));
    }
  }
  __syncthreads();
  mma8(a2, &sY[wv * 16][0], 136, lw2p + 16384, l15, q);
#pragma unroll
  for (int nt = 0; nt < 8; nt++){
    int col = nt * 16 + l15;
    float bval = lb2[col];
#pragma unroll
    for (int rr = 0; rr < 4; rr++){
      int row = wv * 16 + q * 4 + rr;
      int gr = m0 + row, tok = gr >> 3, c = gr & 7;
      float hres = emb[(size_t)tok * 128 + col] + pos[c * 128 + col];
      table[(size_t)gr * 128 + col] = f2b(a2[nt][rr] + bval + hres);
    }
  }
}

// ---------------------------------------------------------------------------
// k_summ (R7-proven, unchanged): summ[ch] = mean_j table[x[ch*8+j]*8+j].
// ---------------------------------------------------------------------------
__global__ __launch_bounds__(256) void k_summ(
    const int* __restrict__ x, const u16* __restrict__ table, u16* __restrict__ summ)
{
  __shared__ int stok[512];
  const int tid = threadIdx.x;
  const int ch0 = blockIdx.x * 64;
  stok[tid] = x[ch0 * 8 + tid];
  stok[tid + 256] = x[ch0 * 8 + 256 + tid];
  __syncthreads();
  const int lc = tid >> 2, sg = tid & 3;
  float acc[32];
#pragma unroll
  for (int i = 0; i < 32; i++) acc[i] = 0.f;
#pragma unroll
  for (int j = 0; j < 8; j++){
    int row = stok[lc * 8 + j] * 8 + j;
    const uint4* t4 = (const uint4*)(table + (size_t)row * 128 + sg * 32);
#pragma unroll
    for (int i = 0; i < 4; i++){
      uint4 v = t4[i];
      unsigned w[4] = {v.x, v.y, v.z, v.w};
#pragma unroll
      for (int k = 0; k < 4; k++){
        acc[i * 8 + k * 2]     += lo2f(w[k]);
        acc[i * 8 + k * 2 + 1] += hi2f(w[k]);
      }
    }
  }
  unsigned* dst = (unsigned*)(summ + (size_t)(ch0 + lc) * 128 + sg * 32);
#pragma unroll
  for (int i = 0; i < 16; i++)
    dst[i] = (unsigned)f2b(acc[2 * i] * 0.125f) | (((unsigned)f2b(acc[2 * i + 1] * 0.125f)) << 16);
}

// ---------------------------------------------------------------------------
// k_rounds v3: pool + 3 rounds (PQ, msg, agg, t2, upd, LN) + bc.
// 256 blocks x 640 threads. mw1 panels PERSISTENT in LDS (staged once);
// all other GEMM B-panels read directly from L2 inside the MFMA loop.
// 6 barriers/round (was 8), zero per-phase staging machinery.
// ---------------------------------------------------------------------------
DEV void mma_tile4(floatx4* acc, const u16* Arow, int ap, const u16* W,
                   int colbase, int l15, int q){
  const u16* ar = Arow + l15 * ap + q * 8;
#pragma unroll
  for (int kk = 0; kk < 4; kk++){
    bf16x8 av = *(const bf16x8*)(ar + kk * 32);
#pragma unroll
    for (int nt = 0; nt < 4; nt++){
      bf16x8 bv = *(const bf16x8*)(W + (size_t)((kk * 128 + colbase + nt * 16 + l15) * 4 + q) * 8);
      acc[nt] = __builtin_amdgcn_mfma_f32_16x16x32_bf16(av, bv, acc[nt], 0, 0, 0);
    }
  }
}

template<bool GELU>
DEV void store_tile4(const floatx4* acc, const float* bias, u16* Crow, int cp,
                     int colbase, int l15, int q){
#pragma unroll
  for (int nt = 0; nt < 4; nt++){
    int col = colbase + nt * 16 + l15;
    float bval = bias ? bias[col] : 0.f;
#pragma unroll
    for (int rr = 0; rr < 4; rr++){
      float v = acc[nt][rr] + bval;
      if (GELU) v = geluf(v);
      Crow[(q * 4 + rr) * cp + col] = f2b(v);
    }
  }
}

__global__ __launch_bounds__(640, 1) void k_rounds(
    const u16* __restrict__ summB,
    const u16* __restrict__ poolp, const float* __restrict__ poolb,
    const u16* __restrict__ mw1p, const float* __restrict__ mb1,
    const u16* __restrict__ mw2p, const float* __restrict__ mb2,
    const u16* __restrict__ uw1p, const float* __restrict__ ub1,
    const u16* __restrict__ uw2p, const float* __restrict__ ub2,
    const float* __restrict__ mlng, const float* __restrict__ mlnb,
    const u16* __restrict__ bcp, const float* __restrict__ bcb,
    u16* __restrict__ bcB)
{
  __shared__ __align__(16) u16 sH[80][136];   // hmsg
  __shared__ __align__(16) u16 sPQ[80][264];  // [P|Q] -> [agg|upd]
  __shared__ __align__(16) u16 sS[80][136];   // summ; msg means; t2
  __shared__ __align__(16) u16 sW[32768];     // persistent mw1a | mw1b
  const int tid = threadIdx.x;
  const int m0 = blockIdx.x * 64;
  const int halo = (m0 & 1023) ? 12 : 0;
  const int lo = m0 - halo;

  // ---- init: persistent mw1 panels (64 KB) + summ rows -> sS ----
  {
    const uint4* gs = (const uint4*)mw1p;
    uint4* ss = (uint4*)sW;
    for (int i = tid; i < 4096; i += 640) ss[i] = gs[i];
#pragma unroll
    for (int k = 0; k < 2; k++){
      int idx = tid + k * 640;
      int rr = idx >> 4, c = idx & 15;
      int node = lo + rr; if (node > 16383) node = 16383;
      *(uint4*)&sS[rr][c * 8] = *(const uint4*)(summB + (size_t)node * 128 + c * 8);
    }
  }
  __syncthreads();

  const int lane = tid & 63, wv = tid >> 6, l15 = lane & 15, q = lane >> 4;
  const int rt = wv >> 1, ch = wv & 1, colbase = ch * 64;
  const int row0 = rt * 16;
  const int d0 = lane * 2;
  const float b1lo = mb1[d0],  b1hi = mb1[d0 + 1];
  const float glo  = mlng[d0], ghi  = mlng[d0 + 1];
  const float blo  = mlnb[d0], bhi  = mlnb[d0 + 1];

  // ---- pool: hmsg = summ @ pool_w + pool_b (B from L2) ----
  {
    floatx4 acc[4];
#pragma unroll
    for (int i = 0; i < 4; i++) acc[i] = (floatx4)(0.0f);
    mma_tile4(acc, &sS[row0][0], 136, poolp, colbase, l15, q);
    store_tile4<false>(acc, poolb, &sH[row0][0], 136, colbase, l15, q);
  }
  __syncthreads();

  for (int rnd = 0; rnd < 3; rnd++){
    { // PQ: sPQ[:, ch*128 .. +128] = hmsg @ mw1[ch-half]  (B from LDS)
      floatx4 acc[8];
#pragma unroll
      for (int i = 0; i < 8; i++) acc[i] = (floatx4)(0.0f);
      mma8(acc, &sH[row0][0], 136, sW + ch * 16384, l15, q);
#pragma unroll
      for (int nt = 0; nt < 8; nt++){
        int col = ch * 128 + nt * 16 + l15;
#pragma unroll
        for (int rr = 0; rr < 4; rr++)
          sPQ[row0 + q * 4 + rr][col] = f2b(acc[nt][rr]);
      }
    }
    __syncthreads();
    { // msg: s[r] = mean_d gelu(P[r] + Q[r-d] + b1), 8 rows/wave
      for (int it = 0; it < 8; it++){
        int rr = wv * 8 + it;
        int i = (lo + rr) & 1023;
        int nd = (i + 1 < 5) ? i + 1 : 5;
        int ndc = (nd < rr + 1) ? nd : rr + 1;   // clamp garbage halo rows
        unsigned pv = *(const unsigned*)&sPQ[rr][d0];
        float p0 = lo2f(pv) + b1lo, p1 = hi2f(pv) + b1hi;
        float a0 = 0.f, a1 = 0.f;
        for (int d = 0; d < ndc; d++){
          unsigned qv = *(const unsigned*)&sPQ[rr - d][128 + d0];
          a0 += geluf(p0 + lo2f(qv));
          a1 += geluf(p1 + hi2f(qv));
        }
        float inv = 1.f / (float)nd;
        unsigned pack = (unsigned)f2b(a0 * inv) | (((unsigned)f2b(a1 * inv)) << 16);
        *(unsigned*)&sS[rr][d0] = pack;
      }
    }
    __syncthreads();
    { // agg: sPQ[:,0:128] = s @ mw2 + mb2  (B from L2; P is dead)
      floatx4 acc[4];
#pragma unroll
      for (int i = 0; i < 4; i++) acc[i] = (floatx4)(0.0f);
      mma_tile4(acc, &sS[row0][0], 136, mw2p, colbase, l15, q);
      store_tile4<false>(acc, mb2, &sPQ[row0][0], 264, colbase, l15, q);
    }
    __syncthreads();
    { // t2: sS = gelu(hmsg @ uw1a + agg @ uw1b + ub1)  (B from L2, fused)
      floatx4 acc[4];
#pragma unroll
      for (int i = 0; i < 4; i++) acc[i] = (floatx4)(0.0f);
      mma_tile4(acc, &sH[row0][0], 136, uw1p, colbase, l15, q);
      mma_tile4(acc, &sPQ[row0][0], 264, uw1p + 16384, colbase, l15, q);
      store_tile4<true>(acc, ub1, &sS[row0][0], 136, colbase, l15, q);
    }
    __syncthreads();
    { // upd: sPQ[:,128:256] = t2 @ uw2 + ub2  (B from L2; Q is dead)
      floatx4 acc[4];
#pragma unroll
      for (int i = 0; i < 4; i++) acc[i] = (floatx4)(0.0f);
      mma_tile4(acc, &sS[row0][0], 136, uw2p, colbase, l15, q);
      store_tile4<false>(acc, ub2, &sPQ[row0][128], 264, colbase, l15, q);
    }
    __syncthreads();
    { // LN: hmsg = LN(hmsg + upd), 8 rows/wave
      for (int it = 0; it < 8; it++){
        int rr = wv * 8 + it;
        unsigned hv = *(const unsigned*)&sH[rr][d0];
        unsigned uv = *(const unsigned*)&sPQ[rr][128 + d0];
        float x0 = lo2f(hv) + lo2f(uv);
        float x1 = hi2f(hv) + hi2f(uv);
        float s = x0 + x1, s2 = x0 * x0 + x1 * x1;
#pragma unroll
        for (int off = 32; off; off >>= 1){
          s  += __shfl_xor(s, off, 64);
          s2 += __shfl_xor(s2, off, 64);
        }
        float mu = s * (1.f / 128.f);
        float rs = rsqrtf(s2 * (1.f / 128.f) - mu * mu + 1e-5f);
        float y0 = (x0 - mu) * rs * glo + blo;
        float y1 = (x1 - mu) * rs * ghi + bhi;
        unsigned pack = (unsigned)f2b(y0) | (((unsigned)f2b(y1)) << 16);
        *(unsigned*)&sH[rr][d0] = pack;
      }
    }
    __syncthreads();
  }
  { // bc = hmsg @ bc_w + bc_b (B from L2), write owned rows only
    floatx4 acc[4];
#pragma unroll
    for (int i = 0; i < 4; i++) acc[i] = (floatx4)(0.0f);
    mma_tile4(acc, &sH[row0][0], 136, bcp, colbase, l15, q);
#pragma unroll
    for (int nt = 0; nt < 4; nt++){
      int col = colbase + nt * 16 + l15;
      float bval = bcb[col];
#pragma unroll
      for (int rr = 0; rr < 4; rr++){
        int row = row0 + q * 4 + rr;
        if (row >= halo && row < halo + 64){
          int node = lo + row;
          bcB[(size_t)node * 128 + col] = f2b(acc[nt][rr] + bval);
        }
      }
    }
  }
}

// ---------------------------------------------------------------------------
// k_head v8: 1024 blocks x 512 threads, 2 blocks/CU (LDS 66 KB, VGPR<=128).
// Single 32 KB weight buffer, both head panels staged sequentially via
// register prefetch. out = LN(table[x]*+bc) @ head_w, f32.
// ---------------------------------------------------------------------------
__global__ __launch_bounds__(512, 2) void k_head(
    const int* __restrict__ x, const u16* __restrict__ table,
    const u16* __restrict__ bcB,
    const float* __restrict__ g, const float* __restrict__ bb,
    const u16* __restrict__ headp, float* __restrict__ out)
{
  __shared__ __align__(16) u16 sA[128][136];
  __shared__ __align__(16) u16 sW[16384];
  const int tid = threadIdx.x;
  const int m0 = blockIdx.x * 128;
  const int r = tid >> 2, sg = tid & 3;
  // prefetch colsA panel
  uint4 pa0, pa1, pa2, pa3;
  {
    const uint4* gs = (const uint4*)headp;
    pa0 = gs[tid]; pa1 = gs[tid + 512]; pa2 = gs[tid + 1024]; pa3 = gs[tid + 1536];
  }
  // ---- phase A: quad-shuffle LN(table-gather + bc) -> sA ----
  {
    const int gr = m0 + r;
    const int trow = x[gr] * 8 + (gr & 7);
    const uint4* l4 = (const uint4*)(table + (size_t)trow * 128 + sg * 32);
    const uint4* c4 = (const uint4*)(bcB + (size_t)(gr >> 3) * 128 + sg * 32);
    float h[32];
    float s = 0.f, s2 = 0.f;
#pragma unroll
    for (int i = 0; i < 4; i++){
      uint4 lv = l4[i], cv = c4[i];
      unsigned lw[4] = {lv.x, lv.y, lv.z, lv.w}, cw[4] = {cv.x, cv.y, cv.z, cv.w};
#pragma unroll
      for (int j = 0; j < 4; j++){
        float v0 = lo2f(lw[j]) + lo2f(cw[j]);
        float v1 = hi2f(lw[j]) + hi2f(cw[j]);
        h[i * 8 + j * 2] = v0; h[i * 8 + j * 2 + 1] = v1;
        s += v0 + v1; s2 += v0 * v0 + v1 * v1;
      }
    }
    s  += __shfl_xor(s, 1, 64);   s  += __shfl_xor(s, 2, 64);
    s2 += __shfl_xor(s2, 1, 64);  s2 += __shfl_xor(s2, 2, 64);
    float mu = s * (1.f / 128.f);
    float rs = rsqrtf(s2 * (1.f / 128.f) - mu * mu + 1e-5f);
#pragma unroll
    for (int i = 0; i < 32; i++){
      int col = sg * 32 + i;
      sA[r][col] = f2b((h[i] - mu) * rs * g[col] + bb[col]);
    }
  }
  // commit colsA; prefetch colsB
  {
    uint4* ss = (uint4*)sW;
    ss[tid] = pa0; ss[tid + 512] = pa1; ss[tid + 1024] = pa2; ss[tid + 1536] = pa3;
  }
  uint4 pb0, pb1, pb2, pb3;
  {
    const uint4* gs = (const uint4*)(headp + 16384);
    pb0 = gs[tid]; pb1 = gs[tid + 512]; pb2 = gs[tid + 1024]; pb3 = gs[tid + 1536];
  }
  __syncthreads();                               // B1: sA + sW(colsA) ready
  const int lane = tid & 63, wv = tid >> 6, l15 = lane & 15, q = lane >> 4;
  { // N-half 0
    floatx4 acc[8];
#pragma unroll
    for (int i = 0; i < 8; i++) acc[i] = (floatx4)(0.0f);
    mma8(acc, &sA[wv * 16][0], 136, sW, l15, q);
#pragma unroll
    for (int nt = 0; nt < 8; nt++){
      int col = nt * 16 + l15;
#pragma unroll
      for (int rr = 0; rr < 4; rr++){
        int row = wv * 16 + q * 4 + rr;
        out[(size_t)(m0 + row) * 256 + col] = acc[nt][rr];
      }
    }
  }
  __syncthreads();                               // B2: all sW reads done
  {
    uint4* ss = (uint4*)sW;
    ss[tid] = pb0; ss[tid + 512] = pb1; ss[tid + 1024] = pb2; ss[tid + 1536] = pb3;
  }
  __syncthreads();                               // B3: sW(colsB) ready
  { // N-half 1
    floatx4 acc[8];
#pragma unroll
    for (int i = 0; i < 8; i++) acc[i] = (floatx4)(0.0f);
    mma8(acc, &sA[wv * 16][0], 136, sW, l15, q);
#pragma unroll
    for (int nt = 0; nt < 8; nt++){
      int col = 128 + nt * 16 + l15;
#pragma unroll
      for (int rr = 0; rr < 4; rr++){
        int row = wv * 16 + q * 4 + rr;
        out[(size_t)(m0 + row) * 256 + col] = acc[nt][rr];
      }
    }
  }
}

// ---------------------------------------------------------------------------

extern "C" void kernel_launch(void* const* d_in, const int* in_sizes, int n_in,
                              void* d_out, int out_size, void* d_ws, size_t ws_size,
                              hipStream_t stream)
{
  const int*   x     = (const int*)d_in[0];
  const float* emb   = (const float*)d_in[1];
  const float* pos   = (const float*)d_in[2];
  const float* lw1   = (const float*)d_in[3];
  const float* lb1   = (const float*)d_in[4];
  const float* lw2   = (const float*)d_in[5];
  const float* lb2   = (const float*)d_in[6];
  const float* llng  = (const float*)d_in[7];
  const float* llnb  = (const float*)d_in[8];
  const float* poolw = (const float*)d_in[9];
  const float* poolb = (const float*)d_in[10];
  const float* mw1   = (const float*)d_in[11];
  const float* mb1   = (const float*)d_in[12];
  const float* mw2   = (const float*)d_in[13];
  const float* mb2   = (const float*)d_in[14];
  const float* uw1   = (const float*)d_in[15];
  const float* ub1   = (const float*)d_in[16];
  const float* uw2   = (const float*)d_in[17];
  const float* ub2   = (const float*)d_in[18];
  const float* mlng  = (const float*)d_in[19];
  const float* mlnb  = (const float*)d_in[20];
  const float* bcw   = (const float*)d_in[21];
  const float* bcb   = (const float*)d_in[22];
  const float* flng  = (const float*)d_in[23];
  const float* flnb  = (const float*)d_in[24];
  const float* headw = (const float*)d_in[25];

  // ws layout (~9.4 MB): packed panels | table | summB | bcB
  char* ws = (char*)d_ws;
  u16* wpack = (u16*)ws;
  u16* lw1p  = wpack;           // colsA; colsB at +16384
  u16* lw2p  = wpack + 32768;   // k-half0; k-half1 at +16384
  u16* poolp = wpack + 65536;
  u16* mw1p  = wpack + 81920;   // P panel; Q panel at +16384 (contiguous 64 KB)
  u16* mw2p  = wpack + 114688;
  u16* uw1p  = wpack + 131072;  // rows 0:128; rows 128:256 at +16384
  u16* uw2p  = wpack + 163840;
  u16* bcp   = wpack + 180224;
  u16* headp = wpack + 196608;  // colsA; colsB at +16384
  u16* table = (u16*)(ws + 524288);        // 2048 x 128 bf16 = 512 KB
  u16* summB = (u16*)(ws + 1048576);       // 16384 x 128 bf16 = 4.19 MB
  u16* bcB   = (u16*)(ws + 5242880);       // 16384 x 128 bf16 = 4.19 MB

  k_pack<<<896, 256, 0, stream>>>(lw1, lw2, poolw, mw1, mw2, uw1, uw2, bcw, headw, wpack);
  k_table<<<32, 256, 0, stream>>>(emb, pos, lw1p, lb1, lw2p, lb2, llng, llnb, table);
  k_summ<<<256, 256, 0, stream>>>(x, table, summB);
  k_rounds<<<256, 640, 0, stream>>>(summB, poolp, poolb, mw1p, mb1, mw2p, mb2,
                                    uw1p, ub1, uw2p, ub2, mlng, mlnb, bcp, bcb, bcB);
  k_head<<<1024, 512, 0, stream>>>(x, table, bcB, flng, flnb, headp, (float*)d_out);
}